// Round 5
// baseline (282.899 us; speedup 1.0000x reference)
//
#include <hip/hip_runtime.h>

// ChineseCLIP vision attention, MI355X bf16-MFMA pipeline. Round 5:
//  - qkv/o_gemm: BK=64 K-loop (16 iters, half the barrier drains) with
//    XOR-swizzled global_load_lds staging (slot ^= row&7 on the GLOBAL side,
//    since LDS side is fixed to lane*16) -> conflict-free ds_read_b128.
//  - attn: K-only LDS (34KB -> 4 blocks/CU), 2 blocks per bh (grid 1024),
//    V frags from global (L3-resident), Q prefetched one qt ahead,
//    softmax in exp2 domain (log2e folded into Q scale).
// B=32, T=257, D=1024, H=16, HD=64.

#define B_   32
#define T_   257
#define TP   272
#define H_   16
#define HD_  64
#define D_   1024
#define NTOK 8224
#define BH_  512
#define FRAG_PER_BH 17408   // TP*HD elements per (b,h) in frag-major arrays

typedef __bf16 bf16;
typedef __bf16 bf16x4 __attribute__((ext_vector_type(4)));
typedef __bf16 bf16x8 __attribute__((ext_vector_type(8)));
typedef short  s16x4  __attribute__((ext_vector_type(4)));
typedef short  s16x8  __attribute__((ext_vector_type(8)));
typedef float  floatx4 __attribute__((ext_vector_type(4)));

static constexpr size_t SZ_XB   = (size_t)NTOK * D_ * 2;
static constexpr size_t SZ_WQKV = (size_t)3 * D_ * D_ * 2;
static constexpr size_t SZ_W    = (size_t)D_ * D_ * 2;
static constexpr size_t SZ_QK   = (size_t)BH_ * FRAG_PER_BH * 2;

static constexpr size_t OFF_XB   = 0;
static constexpr size_t OFF_WQKV = OFF_XB + SZ_XB;
static constexpr size_t OFF_WO   = OFF_WQKV + SZ_WQKV;
static constexpr size_t OFF_Q    = OFF_WO + SZ_W;
static constexpr size_t OFF_K    = OFF_Q + SZ_QK;
static constexpr size_t OFF_V    = OFF_K + SZ_QK;
static constexpr size_t OFF_CTX  = OFF_V + SZ_QK;

// scale for Q: (1/8) * log2(e) so softmax runs in exp2 domain
#define QSCALE 0.18033688011112042f

#define GLD16(gp, lp)                                                        \
  __builtin_amdgcn_global_load_lds(                                          \
      (const __attribute__((address_space(1))) void*)(gp),                   \
      (__attribute__((address_space(3))) void*)(lp), 16, 0, 0)

// ---------------- fp32 -> bf16 casts ----------------
__global__ void cast_bf16_kernel(const float* __restrict__ src,
                                 bf16* __restrict__ dst, int n4) {
  int i = blockIdx.x * blockDim.x + threadIdx.x;
  int stride = gridDim.x * blockDim.x;
  for (int idx = i; idx < n4; idx += stride) {
    float4 v = reinterpret_cast<const float4*>(src)[idx];
    bf16x4 o;
    o[0] = (bf16)v.x; o[1] = (bf16)v.y; o[2] = (bf16)v.z; o[3] = (bf16)v.w;
    reinterpret_cast<bf16x4*>(dst)[idx] = o;
  }
}

__global__ void cast4_kernel(const float* __restrict__ s0, const float* __restrict__ s1,
                             const float* __restrict__ s2, const float* __restrict__ s3,
                             bf16* __restrict__ d0, bf16* __restrict__ d1,
                             bf16* __restrict__ d2, bf16* __restrict__ d3, int n4) {
  const float* s = (blockIdx.y == 0) ? s0 : (blockIdx.y == 1) ? s1
                   : (blockIdx.y == 2) ? s2 : s3;
  bf16* d = (blockIdx.y == 0) ? d0 : (blockIdx.y == 1) ? d1
            : (blockIdx.y == 2) ? d2 : d3;
  int i = blockIdx.x * blockDim.x + threadIdx.x;
  int stride = gridDim.x * blockDim.x;
  for (int idx = i; idx < n4; idx += stride) {
    float4 v = reinterpret_cast<const float4*>(s)[idx];
    bf16x4 o;
    o[0] = (bf16)v.x; o[1] = (bf16)v.y; o[2] = (bf16)v.z; o[3] = (bf16)v.w;
    reinterpret_cast<bf16x4*>(d)[idx] = o;
  }
}

// Frag-major layouts (element offsets within one bh's 17408 elems):
// Q/K (A/B-op of 16x16x32): [kt(17)][dc(8)][ki(16)][8]  (t=kt*16+ki, d=dc*8+e)
// V   (A-op of 16x16x16, dt-paired): [kt(17)][p(2)][q2(4)][d16(16)][dp(2)][ki(4)]
//     t = kt*16 + q2*4 + ki, d = p*32 + dp*16 + d16.

// ---------------- fused QKV GEMM (BK=64, swizzled staging) ----------------
// grid 1560; swizzle: XCD x owns n-tiles {3x..3x+2}; mbase = linear/24.
__global__ __launch_bounds__(256) void qkv_gemm(
    const bf16* __restrict__ xb, const bf16* __restrict__ wqkv,
    const float* __restrict__ bq, const float* __restrict__ bk,
    const float* __restrict__ bv,
    bf16* __restrict__ Qf, bf16* __restrict__ Kf, bf16* __restrict__ Vf) {
  __shared__ bf16 smem[16384];   // K-loop: Ash(8192)+Bsh(8192); epi: 128x72
  bf16* Ash = smem;
  bf16* Bsh = smem + 8192;

  const int linear = blockIdx.x;
  const int nbg = ((linear & 7) * 3 + ((linear >> 3) % 3)) * 128;
  const int mbase = (linear / 24) * 128;
  const int tid = threadIdx.x;
  const int lane = tid & 63;
  const int w = tid >> 6;
  const int wr = w >> 1, wc = w & 1;
  const int n15 = lane & 15, quad = lane >> 4;

  const int r8 = lane >> 3;               // row within 8-row strip
  const int sG = ((lane & 7) ^ r8) * 8;   // swizzled global chunk (elem off)

  floatx4 acc[4][4] = {};

  for (int k0 = 0; k0 < D_; k0 += 64) {
#pragma unroll
    for (int c = 0; c < 4; c++) {
      int rbase = c * 32 + w * 8;
      int rloc = rbase + r8;
      int gm = mbase + rloc; if (gm > NTOK - 1) gm = NTOK - 1;
      GLD16(xb + (size_t)gm * D_ + k0 + sG, Ash + rbase * 64);
      GLD16(wqkv + (size_t)(nbg + rloc) * D_ + k0 + sG, Bsh + rbase * 64);
    }
    __syncthreads();
    bf16x8 af[4][2], bfr[4][2];
    const int sw = n15 & 7;
#pragma unroll
    for (int i = 0; i < 4; i++) {
      int arow = (wr * 64 + i * 16 + n15) * 64;
      int brow = (wc * 64 + i * 16 + n15) * 64;
#pragma unroll
      for (int hh = 0; hh < 2; hh++) {
        int so = ((hh * 4 + quad) ^ sw) * 8;
        af[i][hh]  = *reinterpret_cast<const bf16x8*>(Ash + arow + so);
        bfr[i][hh] = *reinterpret_cast<const bf16x8*>(Bsh + brow + so);
      }
    }
#pragma unroll
    for (int i = 0; i < 4; i++)
#pragma unroll
      for (int j = 0; j < 4; j++) {
        acc[i][j] = __builtin_amdgcn_mfma_f32_16x16x32_bf16(af[i][0], bfr[j][0], acc[i][j], 0, 0, 0);
        acc[i][j] = __builtin_amdgcn_mfma_f32_16x16x32_bf16(af[i][1], bfr[j][1], acc[i][j], 0, 0, 0);
      }
    __syncthreads();
  }

  // ---- epilogue: LDS transpose + coalesced frag-major stores ----
  const int z = nbg >> 10;
  bf16* zdst = (z == 0) ? Qf : (z == 1) ? Kf : Vf;
  const float scale = (z == 0) ? QSCALE : 1.0f;
  const float* bias = (z == 0) ? bq : (z == 1) ? bk : bv;
  const int zoff = nbg & 1023;

  const int bA = mbase / T_;
  const int tA = mbase - bA * T_;
  const int tEndA = (tA + 128 < T_) ? tA + 128 : T_;
  const int tgA0 = tA >> 4;
  const int nA = ((tEndA - 1) >> 4) - tgA0 + 1;
  int nU = nA, tEndB = 0;
  if (tA + 128 > T_ && bA + 1 < B_) {
    tEndB = tA + 128 - T_;
    nU += ((tEndB - 1) >> 4) + 1;
  }

  for (int half = 0; half < 2; half++) {
    if (wc == half) {
#pragma unroll
      for (int i = 0; i < 4; i++)
#pragma unroll
        for (int j = 0; j < 4; j++) {
          int colL = j * 16 + n15;
          float bval = bias[zoff + half * 64 + colL];
#pragma unroll
          for (int r = 0; r < 4; r++) {
            int rowL = wr * 64 + i * 16 + quad * 4 + r;
            smem[rowL * 72 + colL] = (bf16)((acc[i][j][r] + bval) * scale);
          }
        }
    }
    __syncthreads();
    const int h = (zoff >> 6) + half;
    for (int u = w; u < nU; u += 4) {
      int b, tg, tlo, thi;
      if (u < nA) {
        b = bA; tg = tgA0 + u;
        tlo = (tA > tg * 16) ? tA : tg * 16;
        int te = tg * 16 + 16; thi = (te < tEndA) ? te : tEndA;
      } else {
        b = bA + 1; tg = u - nA;
        tlo = tg * 16;
        int te = tg * 16 + 16; thi = (te < tEndB) ? te : tEndB;
      }
      bf16* gb = zdst + (size_t)(b * H_ + h) * FRAG_PER_BH + tg * 1024;
      if (z != 2) {
        int ki = lane & 15, dc = lane >> 4;
        int t = tg * 16 + ki;
        if (t >= tlo && t < thi) {
          int rowL = b * T_ + t - mbase;
          bf16x8 v0 = *reinterpret_cast<const bf16x8*>(smem + rowL * 72 + dc * 8);
          bf16x8 v1 = *reinterpret_cast<const bf16x8*>(smem + rowL * 72 + 32 + dc * 8);
          *reinterpret_cast<bf16x8*>(gb + dc * 128 + ki * 8) = v0;
          *reinterpret_cast<bf16x8*>(gb + 512 + dc * 128 + ki * 8) = v1;
        }
      } else {
        int q2 = (lane >> 4) & 3, d16 = lane & 15;
        int tb = tg * 16 + q2 * 4;
        bool full = (tb >= tlo) && (tb + 3 < thi);
#pragma unroll
        for (int p = 0; p < 2; p++) {
          bf16x8 vv;
#pragma unroll
          for (int dp = 0; dp < 2; dp++)
#pragma unroll
            for (int ki = 0; ki < 4; ki++) {
              int t = tb + ki;
              int rr = (b * T_ + t - mbase) & 127;   // safe for masked elems
              vv[dp * 4 + ki] = smem[rr * 72 + p * 32 + dp * 16 + d16];
            }
          bf16* cp = gb + (p * 4 + q2) * 128 + d16 * 8;
          if (full) {
            *reinterpret_cast<bf16x8*>(cp) = vv;
          } else {
#pragma unroll
            for (int dp = 0; dp < 2; dp++)
#pragma unroll
              for (int ki = 0; ki < 4; ki++) {
                int t = tb + ki;
                if (t >= tlo && t < thi) cp[dp * 4 + ki] = vv[dp * 4 + ki];
              }
          }
        }
      }
    }
    __syncthreads();
  }
}

// ---------------- fused attention ----------------
// grid = 1024: block = (bh, z); z=0 -> q-tiles 0..8, z=1 -> 9..16.
// K staged in LDS (34KB -> 4 blocks/CU); V frags from global; Q prefetched.
__global__ __launch_bounds__(256) void attn_kernel(
    const bf16* __restrict__ Qf, const bf16* __restrict__ Kf,
    const bf16* __restrict__ Vf, bf16* __restrict__ ctx) {
  __shared__ bf16 Ksh[17408];

  const int bid = blockIdx.x;
  const int bh = bid >> 1, z = bid & 1;
  const int tid = threadIdx.x;
  const int lane = tid & 63, w = tid >> 6;
  const int n15 = lane & 15, quad = lane >> 4;
  const int b = bh >> 4, h = bh & 15;

  const bf16* Qb = Qf + (size_t)bh * FRAG_PER_BH;
  const bf16* Kb = Kf + (size_t)bh * FRAG_PER_BH;
  const bf16* Vb = Vf + (size_t)bh * FRAG_PER_BH;

  // stage K: 34 chunks of 1KB
  for (int j = w; j < 34; j += 4) GLD16(Kb + j * 512 + lane * 8, Ksh + j * 512);
  __syncthreads();

  const int fo = quad * 128 + n15 * 8;
  const int lo = z ? 9 : 0, hi = z ? 17 : 9;

  const int qt0 = lo + w;
  bf16x8 cq0 = {}, cq1 = {};
  if (qt0 < hi) {
    cq0 = *reinterpret_cast<const bf16x8*>(Qb + qt0 * 1024 + fo);
    cq1 = *reinterpret_cast<const bf16x8*>(Qb + qt0 * 1024 + 512 + fo);
  }

  for (int qt = qt0; qt < hi; qt += 4) {
    const int nqt = qt + 4;
    bf16x8 nq0 = {}, nq1 = {};
    if (nqt < hi) {
      nq0 = *reinterpret_cast<const bf16x8*>(Qb + nqt * 1024 + fo);
      nq1 = *reinterpret_cast<const bf16x8*>(Qb + nqt * 1024 + 512 + fo);
    }

    floatx4 s[17];
#pragma unroll
    for (int kt = 0; kt < 17; kt++) {
      bf16x8 ka0 = *reinterpret_cast<const bf16x8*>(Ksh + kt * 1024 + fo);
      bf16x8 ka1 = *reinterpret_cast<const bf16x8*>(Ksh + kt * 1024 + 512 + fo);
      floatx4 c = {};
      c = __builtin_amdgcn_mfma_f32_16x16x32_bf16(ka0, cq0, c, 0, 0, 0);
      c = __builtin_amdgcn_mfma_f32_16x16x32_bf16(ka1, cq1, c, 0, 0, 0);
      s[kt] = c;
    }
    // keys 257..271 invalid: tile 16 holds keys 256+quad*4+r; only 256 valid
    s[16][1] = -1e30f; s[16][2] = -1e30f; s[16][3] = -1e30f;
    if (quad != 0) s[16][0] = -1e30f;

    float m0 = -1e30f;
#pragma unroll
    for (int kt = 0; kt < 17; kt++)
#pragma unroll
      for (int r = 0; r < 4; r++) m0 = fmaxf(m0, s[kt][r]);
    m0 = fmaxf(m0, __shfl_xor(m0, 16));
    m0 = fmaxf(m0, __shfl_xor(m0, 32));

    float sum = 0.f;
    s16x4 pb[17];
#pragma unroll
    for (int kt = 0; kt < 17; kt++) {
      bf16x4 ph;
#pragma unroll
      for (int r = 0; r < 4; r++) {
        float p = exp2f(s[kt][r] - m0);   // scores pre-scaled by log2(e)/8
        sum += p;
        ph[r] = (bf16)p;
      }
      pb[kt] = __builtin_bit_cast(s16x4, ph);
    }
    sum += __shfl_xor(sum, 16);
    sum += __shfl_xor(sum, 32);

    floatx4 o[4] = {};
#pragma unroll
    for (int kt = 0; kt < 17; kt++) {
#pragma unroll
      for (int p = 0; p < 2; p++) {
        bf16x8 vv = *reinterpret_cast<const bf16x8*>(
            Vb + ((kt * 2 + p) * 4 + quad) * 128 + n15 * 8);
        s16x8 v16 = __builtin_bit_cast(s16x8, vv);
        s16x4 vlo = __builtin_shufflevector(v16, v16, 0, 1, 2, 3);
        s16x4 vhi = __builtin_shufflevector(v16, v16, 4, 5, 6, 7);
        o[p * 2]     = __builtin_amdgcn_mfma_f32_16x16x16bf16_1k(vlo, pb[kt], o[p * 2], 0, 0, 0);
        o[p * 2 + 1] = __builtin_amdgcn_mfma_f32_16x16x16bf16_1k(vhi, pb[kt], o[p * 2 + 1], 0, 0, 0);
      }
    }

    int q = qt * 16 + n15;
    if (q < T_) {
      float inv = 1.0f / sum;
      size_t ob = ((size_t)(b * T_ + q)) * D_ + h * 64 + quad * 4;
#pragma unroll
      for (int dt = 0; dt < 4; dt++) {
        bf16x4 ov;
#pragma unroll
        for (int r = 0; r < 4; r++) ov[r] = (bf16)(o[dt][r] * inv);
        *reinterpret_cast<bf16x4*>(ctx + ob + dt * 16) = ov;
      }
    }
    cq0 = nq0; cq1 = nq1;
  }
}

// ---------------- output projection GEMM (BK=64, fp32 out) ----------------
__global__ __launch_bounds__(256) void o_gemm(
    const bf16* __restrict__ ctx, const bf16* __restrict__ wo,
    const float* __restrict__ bo, float* __restrict__ out) {
  __shared__ bf16 smem[16384];
  bf16* Ash = smem;
  bf16* Bsh = smem + 8192;

  const int linear = blockIdx.x;
  const int nbase = (linear & 7) * 128;
  const int mbase = (linear >> 3) * 128;
  const int tid = threadIdx.x;
  const int lane = tid & 63;
  const int w = tid >> 6;
  const int wr = w >> 1, wc = w & 1;
  const int n15 = lane & 15, quad = lane >> 4;

  const int r8 = lane >> 3;
  const int sG = ((lane & 7) ^ r8) * 8;

  floatx4 acc[4][4] = {};

  for (int k0 = 0; k0 < D_; k0 += 64) {
#pragma unroll
    for (int c = 0; c < 4; c++) {
      int rbase = c * 32 + w * 8;
      int rloc = rbase + r8;
      int gm = mbase + rloc; if (gm > NTOK - 1) gm = NTOK - 1;
      GLD16(ctx + (size_t)gm * D_ + k0 + sG, Ash + rbase * 64);
      GLD16(wo + (size_t)(nbase + rloc) * D_ + k0 + sG, Bsh + rbase * 64);
    }
    __syncthreads();
    bf16x8 af[4][2], bfr[4][2];
    const int sw = n15 & 7;
#pragma unroll
    for (int i = 0; i < 4; i++) {
      int arow = (wr * 64 + i * 16 + n15) * 64;
      int brow = (wc * 64 + i * 16 + n15) * 64;
#pragma unroll
      for (int hh = 0; hh < 2; hh++) {
        int so = ((hh * 4 + quad) ^ sw) * 8;
        af[i][hh]  = *reinterpret_cast<const bf16x8*>(Ash + arow + so);
        bfr[i][hh] = *reinterpret_cast<const bf16x8*>(Bsh + brow + so);
      }
    }
#pragma unroll
    for (int i = 0; i < 4; i++)
#pragma unroll
      for (int j = 0; j < 4; j++) {
        acc[i][j] = __builtin_amdgcn_mfma_f32_16x16x32_bf16(af[i][0], bfr[j][0], acc[i][j], 0, 0, 0);
        acc[i][j] = __builtin_amdgcn_mfma_f32_16x16x32_bf16(af[i][1], bfr[j][1], acc[i][j], 0, 0, 0);
      }
    __syncthreads();
  }

#pragma unroll
  for (int i = 0; i < 4; i++) {
    int rowb = mbase + wr * 64 + i * 16 + quad * 4;
#pragma unroll
    for (int j = 0; j < 4; j++) {
      int col = nbase + wc * 64 + j * 16 + n15;
      float bval = bo[col];
#pragma unroll
      for (int r = 0; r < 4; r++) {
        int m = rowb + r;
        if (m < NTOK) out[(size_t)m * D_ + col] = acc[i][j][r] + bval;
      }
    }
  }
}

extern "C" void kernel_launch(void* const* d_in, const int* in_sizes, int n_in,
                              void* d_out, int out_size, void* d_ws, size_t ws_size,
                              hipStream_t stream) {
  const float* hs = (const float*)d_in[0];
  const float* Wq = (const float*)d_in[1];
  const float* bq = (const float*)d_in[2];
  const float* Wk = (const float*)d_in[3];
  const float* bk = (const float*)d_in[4];
  const float* Wv = (const float*)d_in[5];
  const float* bv = (const float*)d_in[6];
  const float* Wo = (const float*)d_in[7];
  const float* bo = (const float*)d_in[8];

  char* ws = (char*)d_ws;
  bf16* xb   = (bf16*)(ws + OFF_XB);
  bf16* wqkv = (bf16*)(ws + OFF_WQKV);
  bf16* wob  = (bf16*)(ws + OFF_WO);
  bf16* Qfw  = (bf16*)(ws + OFF_Q);
  bf16* Kfw  = (bf16*)(ws + OFF_K);
  bf16* Vfw  = (bf16*)(ws + OFF_V);
  bf16* ctx  = (bf16*)(ws + OFF_CTX);

  cast_bf16_kernel<<<2048, 256, 0, stream>>>(hs, xb, NTOK * D_ / 4);
  cast4_kernel<<<dim3(256, 4), 256, 0, stream>>>(
      Wq, Wk, Wv, Wo,
      wqkv, wqkv + (size_t)D_ * D_, wqkv + (size_t)2 * D_ * D_, wob,
      D_ * D_ / 4);

  qkv_gemm<<<1560, 256, 0, stream>>>(xb, wqkv, bq, bk, bv, Qfw, Kfw, Vfw);
  attn_kernel<<<1024, 256, 0, stream>>>(Qfw, Kfw, Vfw, ctx);
  o_gemm<<<520, 256, 0, stream>>>(ctx, wob, bo, (float*)d_out);
}